// Round 7
// baseline (186.586 us; speedup 1.0000x reference)
//
#include <hip/hip_runtime.h>
#include <stdint.h>

#define B_ 4
#define T_ 4096
#define D_ 512
#define H_ 8
#define HD_ 64
#define W_ 5
#define M_ (B_*T_)     // 16384 rows
#define TILE 128       // tokens per block
#define HALO 16        // >= dil*W/2 margin; TMg rounds to 160
#define TMg 160        // GEMM rows: TILE + 2*HALO
#define TN 192         // qh|kh|vh
#define LSTR 72        // attn LDS row stride (16B-aligned, breaks conflicts)

// GEMM phase LDS: A double-buffer only. Each buffer = 160 rows x 64 k,
// stored as two 32-k halves of 64B rows (global_load_lds contiguity).
#define AHALF 5120     // shorts per 32-k half (160*32)
#define ABUF  10240    // shorts per buffer (2 halves)
// attn overlay: Qs[128*72] Ks[160*72] Vs[160*72] = 32256 shorts (64512 B)
#define SH_ELEMS 32256

typedef __attribute__((ext_vector_type(8))) short short8;
typedef __attribute__((ext_vector_type(4))) float floatx4;

__device__ __forceinline__ unsigned short f2bf(float f) {
    unsigned int u = __builtin_bit_cast(unsigned int, f);
    u += 0x7fffu + ((u >> 16) & 1u);          // RNE
    return (unsigned short)(u >> 16);
}
__device__ __forceinline__ float bf2f(unsigned short s) {
    unsigned int u = ((unsigned int)s) << 16;
    return __builtin_bit_cast(float, u);
}
__device__ __forceinline__ void load8bf(const unsigned short* p, float* f) {
    uint4 d = *(const uint4*)p;
    f[0] = bf2f((unsigned short)(d.x & 0xffffu));
    f[1] = bf2f((unsigned short)(d.x >> 16));
    f[2] = bf2f((unsigned short)(d.y & 0xffffu));
    f[3] = bf2f((unsigned short)(d.y >> 16));
    f[4] = bf2f((unsigned short)(d.z & 0xffffu));
    f[5] = bf2f((unsigned short)(d.z >> 16));
    f[6] = bf2f((unsigned short)(d.w & 0xffffu));
    f[7] = bf2f((unsigned short)(d.w >> 16));
}

// async global->LDS, 16B/lane; LDS dest = wave-uniform base + lane*16
__device__ __forceinline__ void async16(const unsigned short* g, unsigned short* l) {
    __builtin_amdgcn_global_load_lds(
        (const __attribute__((address_space(1))) unsigned int*)g,
        (__attribute__((address_space(3))) unsigned int*)l, 16, 0, 0);
}

// ------------- prep: convert X (fp32->bf16) + build Wt2 ------------------
__global__ __launch_bounds__(256) void prep(const float* __restrict__ x,
                                            const float* __restrict__ Wq,
                                            const float* __restrict__ Wk,
                                            const float* __restrict__ Wv,
                                            unsigned short* __restrict__ xb,
                                            unsigned short* __restrict__ Wt2) {
    int bx = blockIdx.x;
    if (bx < 4096) {
        int i = bx * 256 + threadIdx.x;
        const float4* x4 = (const float4*)x;
        float4 a = x4[2*i], b = x4[2*i + 1];
        uint4 o;
        o.x = (unsigned)f2bf(a.x) | ((unsigned)f2bf(a.y) << 16);
        o.y = (unsigned)f2bf(a.z) | ((unsigned)f2bf(a.w) << 16);
        o.z = (unsigned)f2bf(b.x) | ((unsigned)f2bf(b.y) << 16);
        o.w = (unsigned)f2bf(b.z) | ((unsigned)f2bf(b.w) << 16);
        ((uint4*)xb)[i] = o;
    } else {
        int tid = (bx - 4096) * 256 + threadIdx.x;   // 1536*64 threads
        int np = tid % 1536;                         // h*192 + n192
        int kc = tid / 1536;                         // k chunk of 8
        int h = np / 192, n192 = np % 192;
        int sel = n192 >> 6, ch = n192 & 63;
        int c = h * 64 + ch;
        const float* Wsrc = (sel == 0) ? Wq : ((sel == 1) ? Wk : Wv);
        unsigned short us[8];
#pragma unroll
        for (int j = 0; j < 8; j++)
            us[j] = f2bf(Wsrc[(size_t)(kc*8 + j) * D_ + c]);
        uint4 o;
        o.x = (unsigned)us[0] | ((unsigned)us[1] << 16);
        o.y = (unsigned)us[2] | ((unsigned)us[3] << 16);
        o.z = (unsigned)us[4] | ((unsigned)us[5] << 16);
        o.w = (unsigned)us[6] | ((unsigned)us[7] << 16);
        *(uint4*)(Wt2 + (size_t)np * D_ + kc*8) = o;
    }
}

// -------- fused per-head QKV GEMM + windowed attention --------------------
// grid 1024 = 128 token-tiles x 8 heads. GEMM phase restructure (AITER
// lesson): B frags load global->VGPR directly (L2-resident weights, exact
// MFMA B layout, vmcnt(N)-scheduled, consumed in-iter); only A is staged
// to LDS (double-buffered, prefetched one iter ahead -> tiny barrier drain).
__global__ __launch_bounds__(512, 4) void fused_qkv_attn(
    const unsigned short* __restrict__ Xb,   // [M_,512] bf16
    const unsigned short* __restrict__ Wt2,  // [8,192,512] bf16
    const float* __restrict__ bq, const float* __restrict__ bk2,
    const float* __restrict__ bv, const float* __restrict__ Er,
    const int* __restrict__ layer_p,
    float* __restrict__ out,                 // [B_,T_,512] fp32
    float* __restrict__ attn_out)            // [B_,8,T_,5] fp32
{
    __shared__ unsigned short SH[SH_ELEMS];        // 64512 B union
    __shared__ float sEr[HD_ * W_];
    unsigned short* Qs = SH;                       // attn phase overlay
    unsigned short* Ks = SH + TILE * LSTR;
    unsigned short* Vs = SH + (TILE + TMg) * LSTR;

    const int tid = threadIdx.x;
    const int wave = tid >> 6, lane = tid & 63;
    const int tile = blockIdx.x >> 3, h = blockIdx.x & 7;
    const int b = tile >> 5;                 // 32 tiles per batch
    const int t0 = (tile & 31) * TILE;
    const long m0g = (long)b * T_ + t0;

    for (int i = tid; i < HD_ * W_; i += 512)
        sEr[i] = Er[h * HD_ * W_ + i];

    // A staging jobs: 20 per BK=64 iter (10 row-groups x 2 k-halves);
    // job J = wave + 8*j -> q = J>>1 (16-row group), hh = J&1 (k-half).
    const unsigned short* agA[3];
    unsigned short* alA[3];                  // buf0 dst; buf1 = +ABUF
    int nA = 0;
#pragma unroll
    for (int j = 0; j < 3; j++) {
        int J = wave + 8 * j;
        if (J < 20) {
            int q = J >> 1, hh = J & 1;
            long grow = m0g - HALO + q*16 + (lane >> 2);
            grow = grow < 0 ? 0 : (grow >= M_ ? M_ - 1 : grow);  // halo clamp; masked later
            agA[nA] = Xb + grow * D_ + hh*32 + (lane & 3) * 8;
            alA[nA] = SH + hh * AHALF + q * 512 + lane * 8;
            nA++;
        }
    }

    // B frag base pointers: exact MFMA B-operand layout from global.
    const int wm = (wave >> 2) * 80, wn = (wave & 3) * 48;
    const int qd = lane >> 4, r16 = lane & 15;
    const unsigned short* bsrc[3];
#pragma unroll
    for (int ni = 0; ni < 3; ni++)
        bsrc[ni] = Wt2 + ((size_t)(h * TN + wn + ni*16 + r16)) * D_ + qd * 8;

    // prologue: stage A(it=0) into buf0
#pragma unroll
    for (int j = 0; j < 3; j++)
        if (j < nA) async16(agA[j], alA[j]);
    __syncthreads();

    floatx4 acc[5][3] = {};

#pragma unroll
    for (int it = 0; it < 8; it++) {         // BK=64
        const int kc = it * 64;
        const unsigned short* Abuf = SH + (it & 1) * ABUF;

        // B loads for this iter (global->VGPR, in-iter consumption)
        short8 bf[2][3];
#pragma unroll
        for (int hh = 0; hh < 2; hh++)
#pragma unroll
            for (int ni = 0; ni < 3; ni++)
                bf[hh][ni] = __builtin_bit_cast(short8,
                    *(const uint4*)(bsrc[ni] + kc + hh*32));

        // prefetch A(it+1) into the other buffer (drained at the barrier,
        // a full MFMA stretch later)
        if (it < 7) {
#pragma unroll
            for (int j = 0; j < 3; j++)
                if (j < nA)
                    async16(agA[j] + kc + 64, alA[j] + ((it + 1) & 1) * ABUF);
        }

#pragma unroll
        for (int hh = 0; hh < 2; hh++) {
            short8 af[5];
#pragma unroll
            for (int mi = 0; mi < 5; mi++)
                af[mi] = __builtin_bit_cast(short8,
                    *(const uint4*)(Abuf + hh*AHALF + (wm + mi*16 + r16)*32 + qd*8));
#pragma unroll
            for (int mi = 0; mi < 5; mi++)
#pragma unroll
                for (int ni = 0; ni < 3; ni++)
                    acc[mi][ni] = __builtin_amdgcn_mfma_f32_16x16x32_bf16(
                        af[mi], bf[hh][ni], acc[mi][ni], 0, 0, 0);
        }
        __syncthreads();
    }

    // ---- epilogue: +bias, scatter to Q/K/V LDS tiles (overlays A dbuf) ---
#pragma unroll
    for (int ni = 0; ni < 3; ni++) {
        int n192 = wn + ni * 16 + r16;
        int sel = n192 >> 6;                 // uniform per (wave, ni)
        int ch = n192 & 63;
        float bias = (sel == 0) ? bq[h*64 + ch]
                   : (sel == 1) ? bk2[h*64 + ch] : bv[h*64 + ch];
#pragma unroll
        for (int mi = 0; mi < 5; mi++)
#pragma unroll
            for (int r = 0; r < 4; r++) {
                int l = wm + mi*16 + qd*4 + r;    // 0..159
                unsigned short vb = f2bf(acc[mi][ni][r] + bias);
                if (sel == 0) {
                    if (l >= HALO && l < HALO + TILE)
                        Qs[(l - HALO) * LSTR + ch] = vb;
                } else if (sel == 1) {
                    Ks[l * LSTR + ch] = vb;
                } else {
                    Vs[l * LSTR + ch] = vb;
                }
            }
    }
    __syncthreads();

    // ---- attention from LDS: 8 lanes/token, 2 passes of 64 tokens --------
    const int dil = 1 << layer_p[0];
    const int sh = (h < 4) ? 0 : (h == 4 ? -2 : (h == 5 ? -1 : (h == 6 ? 1 : 2)));
    const int c8 = tid & 7, g64 = tid >> 3;  // 64 token-groups

#pragma unroll
    for (int p = 0; p < 2; p++) {
        int tl = g64 + p * 64;               // local token 0..127
        int t = t0 + tl;
        float qf[8]; load8bf(Qs + tl * LSTR + c8 * 8, qf);

        int pos[W_]; bool val[W_]; float s[W_];
#pragma unroll
        for (int w = 0; w < W_; w++) {
            pos[w] = t + (sh + w - 2) * dil;
            val[w] = (pos[w] >= 0) && (pos[w] < T_);
            float a = 0.f;
            if (val[w]) {
                float kf[8]; load8bf(Ks + (pos[w] - t0 + HALO) * LSTR + c8 * 8, kf);
#pragma unroll
                for (int j = 0; j < 8; j++) a = fmaf(qf[j], kf[j], a);
            }
#pragma unroll
            for (int j = 0; j < 8; j++)
                a = fmaf(qf[j], sEr[(c8*8 + j) * W_ + w], a);
            s[w] = a;
        }
#pragma unroll
        for (int off = 4; off > 0; off >>= 1)
#pragma unroll
            for (int w = 0; w < W_; w++)
                s[w] += __shfl_xor(s[w], off, 8);

        float logit[W_], mx = -1e30f;
#pragma unroll
        for (int w = 0; w < W_; w++) {
            logit[w] = val[w] ? s[w] * 0.125f : -1e30f;
            mx = fmaxf(mx, logit[w]);
        }
        float pw[W_], ssum = 0.f;
#pragma unroll
        for (int w = 0; w < W_; w++) {
            pw[w] = val[w] ? __expf(logit[w] - mx) : 0.f;
            ssum += pw[w];
        }
        const float inv = 1.f / ssum;
        float aw[W_];
#pragma unroll
        for (int w = 0; w < W_; w++) aw[w] = pw[w] * inv;

        if (c8 < W_)
            attn_out[((size_t)(b * H_ + h) * T_ + t) * W_ + c8] = aw[c8];

        float of[8] = {0,0,0,0,0,0,0,0};
#pragma unroll
        for (int w = 0; w < W_; w++) {
            if (val[w]) {
                float vf[8]; load8bf(Vs + (pos[w] - t0 + HALO) * LSTR + c8 * 8, vf);
#pragma unroll
                for (int j = 0; j < 8; j++) of[j] = fmaf(aw[w], vf[j], of[j]);
            }
        }
        float* orow = out + ((size_t)b * T_ + t) * D_ + h * HD_ + c8 * 8;
        *(float4*)(orow)     = make_float4(of[0], of[1], of[2], of[3]);
        *(float4*)(orow + 4) = make_float4(of[4], of[5], of[6], of[7]);
    }
}

extern "C" void kernel_launch(void* const* d_in, const int* in_sizes, int n_in,
                              void* d_out, int out_size, void* d_ws, size_t ws_size,
                              hipStream_t stream) {
    const float* x   = (const float*)d_in[0];
    const float* Wq  = (const float*)d_in[1];
    const float* bq  = (const float*)d_in[2];
    const float* Wk  = (const float*)d_in[3];
    const float* bk  = (const float*)d_in[4];
    const float* Wv  = (const float*)d_in[5];
    const float* bv  = (const float*)d_in[6];
    const float* Er  = (const float*)d_in[7];
    const int* layer = (const int*)d_in[8];

    char* ws = (char*)d_ws;
    unsigned short* Xb  = (unsigned short*)ws;                          // 16 MB
    unsigned short* Wt2 = (unsigned short*)(ws + (size_t)16*1024*1024); // 1.5 MB

    float* out  = (float*)d_out;
    float* attn = out + (size_t)B_ * T_ * D_;

    prep<<<4096 + 384, 256, 0, stream>>>(x, Wq, Wk, Wv, Xb, Wt2);
    fused_qkv_attn<<<(M_ / TILE) * 8, 512, 0, stream>>>(Xb, Wt2, bq, bk, bv,
                                                        Er, layer, out, attn);
}